// Round 17
// baseline (600.902 us; speedup 1.0000x reference)
//
#include <hip/hip_runtime.h>
#include <hip/hip_bf16.h>
#include <stdint.h>

typedef __bf16 bf16;
typedef bf16 bf16x8 __attribute__((ext_vector_type(8)));
typedef float f32x4 __attribute__((ext_vector_type(4)));

#define N_NODES 50000
#define FEAT 128
#define NB_SCAN ((N_NODES + 511) / 512)   // 98 (512-thread scan blocks)
#define EDGE_BLOCKS 2048

static constexpr size_t UV_BYTES    = (size_t)N_NODES * 256 * 2;    // 25.6 MB bf16 uv
static constexpr size_t INBOX_BYTES = (size_t)N_NODES * FEAT * 4;   // 25.6 MB f32 inbox

#define WUV_OFF 0        // [256][128]  combined (mw1 top|bottom) transposed
#define WM2_OFF 32768    // [128][128]
#define WM3_OFF 49152    // [128][128]
#define WN1_OFF 65536    // [128][256]
#define WN2_OFF 98304    // [128][128]
#define WN3_OFF 114688   // [128][128]
#define W_TOTAL 131072
static constexpr size_t W_BYTES = (size_t)W_TOTAL * 2;
#define PREP_BLOCKS ((W_TOTAL + 255) / 256)   // 512

__device__ __forceinline__ bf16x8 cvt_f32x8_bf16(const float* __restrict__ p) {
  float4 f0 = *(const float4*)p;
  float4 f1 = *(const float4*)(p + 4);
  bf16x8 t;
  t[0] = (bf16)f0.x; t[1] = (bf16)f0.y; t[2] = (bf16)f0.z; t[3] = (bf16)f0.w;
  t[4] = (bf16)f1.x; t[5] = (bf16)f1.y; t[6] = (bf16)f1.z; t[7] = (bf16)f1.w;
  return t;
}

// ---------------- fused: prep weights (blocks [0,512)) + hist (rest) ----------------
__global__ void prep_hist_kernel(const float* __restrict__ mw1, const float* __restrict__ mw2,
                                 const float* __restrict__ mw3, const float* __restrict__ nw1,
                                 const float* __restrict__ nw2, const float* __restrict__ nw3,
                                 bf16* __restrict__ w,
                                 const int* __restrict__ receivers, int* __restrict__ cnt, int E) {
  const int b = blockIdx.x;
  if (b < PREP_BLOCKS) {
    int i = b * 256 + threadIdx.x;
    if (i >= W_TOTAL) return;
    float v;
    if (i < WM2_OFF) {
      int c = i >> 7, k = i & 127;
      v = (c < 128) ? mw1[k * 128 + c] : mw1[(128 + k) * 128 + (c - 128)];
    } else if (i < WM3_OFF) {
      int j = i - WM2_OFF; int c = j >> 7, k = j & 127;
      v = mw2[k * 128 + c];
    } else if (i < WN1_OFF) {
      int j = i - WM3_OFF; int c = j >> 7, k = j & 127;
      v = mw3[k * 128 + c];
    } else if (i < WN2_OFF) {
      int j = i - WN1_OFF; int c = j >> 8, k = j & 255;
      v = nw1[k * 128 + c];
    } else if (i < WN3_OFF) {
      int j = i - WN2_OFF; int c = j >> 7, k = j & 127;
      v = nw2[k * 128 + c];
    } else {
      int j = i - WN3_OFF; int c = j >> 7, k = j & 127;
      v = nw3[k * 128 + c];
    }
    w[i] = (bf16)v;
  } else {
    int i = (b - PREP_BLOCKS) * 256 + threadIdx.x;
    if (i < E) atomicAdd(&cnt[receivers[i]], 1);
  }
}

// ---------------- scan1: 512-thread blocks over 50k counts ----------------
__global__ __launch_bounds__(512) void scan1_kernel(const int* __restrict__ cnt,
                                                    int* __restrict__ offs,
                                                    int* __restrict__ bsum) {
  __shared__ int s[512];
  const int tid = threadIdx.x;
  const int g = blockIdx.x * 512 + tid;
  int x = (g < N_NODES) ? cnt[g] : 0;
  s[tid] = x;
  __syncthreads();
  for (int off = 1; off < 512; off <<= 1) {
    int v = (tid >= off) ? s[tid - off] : 0;
    __syncthreads();
    s[tid] += v;
    __syncthreads();
  }
  if (g < N_NODES) offs[g] = s[tid] - x;
  if (tid == 511) bsum[blockIdx.x] = s[tid];
}

__global__ void scan2_kernel(int* __restrict__ bsum) {  // 1 block x 128, NB_SCAN=98
  __shared__ int s[128];
  const int tid = threadIdx.x;
  int x = (tid < NB_SCAN) ? bsum[tid] : 0;
  s[tid] = x;
  __syncthreads();
  for (int off = 1; off < 128; off <<= 1) {
    int v = (tid >= off) ? s[tid - off] : 0;
    __syncthreads();
    s[tid] += v;
    __syncthreads();
  }
  if (tid < NB_SCAN) bsum[tid] = s[tid] - x;
}

// ---------------- mega dispatch: scatter_ids(int2) + inbox_init + uv_gemm ----------------
__global__ __launch_bounds__(512) void scatter_inbox_uv_kernel(
    const int* __restrict__ senders, const int* __restrict__ receivers,
    const int* __restrict__ offs, const int* __restrict__ bsum, int* __restrict__ cur,
    int2* __restrict__ sPair,
    const int* __restrict__ cnt, const float* __restrict__ mb3, float* __restrict__ inbox,
    const float* __restrict__ nodes, const bf16* __restrict__ wuvt,
    const float* __restrict__ mb1, bf16* __restrict__ uv, int E) {
  const int SC = (E + 511) >> 9;
  const int IB = (N_NODES * 32 + 511) >> 9;
  const int b = blockIdx.x;
  const int tid = threadIdx.x;

  if (b < SC) {
    int i = b * 512 + tid;
    if (i < E) {
      int r = receivers[i];
      int slot = offs[r] + bsum[r >> 9] + atomicAdd(&cur[r], 1);
      sPair[slot] = make_int2(senders[i], r);   // one 8B random write
    }
    return;
  }
  if (b < SC + IB) {
    int i = (b - SC) * 512 + tid;
    if (i >= N_NODES * 32) return;
    int n = i >> 5, q = i & 31;
    float c = (float)cnt[n];
    float4 bb = *(const float4*)(mb3 + q * 4);
    float4 o = {c * bb.x, c * bb.y, c * bb.z, c * bb.w};
    *(float4*)(inbox + (size_t)n * FEAT + q * 4) = o;
    return;
  }

  // ---- uv = nodes @ [W1a | W1b] (+b1 on u-half), bf16 out ----
  const int ub = b - SC - IB;
  const int lane = tid & 63, wid = tid >> 6;
  const int wm = wid >> 2, wn = wid & 3;
  const int rBase = ub * 128 + wm * 64;
  const int cBase = wn * 64;
  const int l15 = lane & 15, ka = (lane >> 4) * 8, rj = (lane >> 4) * 4;

  f32x4 acc[4][4];
#pragma unroll
  for (int mi = 0; mi < 4; ++mi)
#pragma unroll
    for (int ni = 0; ni < 4; ++ni) acc[mi][ni] = (f32x4){0.f, 0.f, 0.f, 0.f};

#pragma unroll
  for (int kk = 0; kk < 4; ++kk) {
    const int k0 = kk * 32 + ka;
    bf16x8 a[4], bb[4];
#pragma unroll
    for (int mi = 0; mi < 4; ++mi) {
      int r = rBase + mi * 16 + l15;
      if (r > N_NODES - 1) r = N_NODES - 1;
      a[mi] = cvt_f32x8_bf16(nodes + (size_t)r * FEAT + k0);
    }
#pragma unroll
    for (int ni = 0; ni < 4; ++ni) {
      int c = cBase + ni * 16 + l15;
      bb[ni] = *(const bf16x8*)(wuvt + (size_t)c * 128 + k0);
    }
#pragma unroll
    for (int mi = 0; mi < 4; ++mi)
#pragma unroll
      for (int ni = 0; ni < 4; ++ni)
        acc[mi][ni] = __builtin_amdgcn_mfma_f32_16x16x32_bf16(a[mi], bb[ni], acc[mi][ni], 0, 0, 0);
  }
#pragma unroll
  for (int mi = 0; mi < 4; ++mi)
#pragma unroll
    for (int ni = 0; ni < 4; ++ni) {
      int c = cBase + ni * 16 + l15;
      float bias = (c < FEAT) ? mb1[c] : 0.f;
#pragma unroll
      for (int j = 0; j < 4; ++j) {
        int r = rBase + mi * 16 + rj + j;
        if (r < N_NODES) uv[(size_t)r * 256 + c] = (bf16)(acc[mi][ni][j] + bias);
      }
    }
}

// ---- segmented reduce from accumulators: sorted ids -> ballot mask -> shfl combine ----
__device__ __forceinline__ void seg_reduce(const f32x4 (&acc3)[2][8], int idr,
                                           int lane, int l15, int rj,
                                           float* __restrict__ inbox) {
  int nxt = __shfl(idr, (lane & 31) + 1);
  bool bnd = ((lane & 31) == 31) || (idr != nxt);
  unsigned long long bm = __ballot(bnd);
  uint32_t mask = (uint32_t)(bm & 0xffffffffull);
  int lo = 0;
  while (mask) {
    int hi = __ffs(mask) - 1;   // inclusive boundary row
    mask &= mask - 1;
    int recv = __shfl(idr, hi);
    if (recv >= 0) {
      float s[8];
#pragma unroll
      for (int ni = 0; ni < 8; ++ni) {
        float x = 0.f;
#pragma unroll
        for (int mi = 0; mi < 2; ++mi)
#pragma unroll
          for (int j = 0; j < 4; ++j) {
            int row = mi * 16 + rj + j;
            x += (row >= lo && row <= hi) ? acc3[mi][ni][j] : 0.f;
          }
        x += __shfl_xor(x, 16);
        x += __shfl_xor(x, 32);
        s[ni] = x;
      }
      if (lane < 16) {
        float* dst = inbox + (size_t)recv * FEAT + l15;
#pragma unroll
        for (int ni = 0; ni < 8; ++ni) unsafeAtomicAdd(dst + ni * 16, s[ni]);
      }
    }
    lo = hi + 1;
  }
}

// ---------------- edge kernel v13: v12 body in a grid-stride loop (2048 blocks) ----------------
// 256 thr = 4 waves; each wave loops over 32-edge tiles; every iteration self-contained.
__global__ __launch_bounds__(256, 3) void edge_kernel(const bf16* __restrict__ uv,
                                                      const int2* __restrict__ sPair,
                                                      const bf16* __restrict__ wm2t,
                                                      const bf16* __restrict__ wm3t,
                                                      const float* __restrict__ mb2,
                                                      float* __restrict__ inbox, int E) {
  __shared__ bf16 hbuf[4][16 * 128];  // 4KB per-wave half-tile transpose slice
  const int tid = threadIdx.x, lane = tid & 63, wid = tid >> 6;
  const int l15 = lane & 15, ka = (lane >> 4) * 8, rj = (lane >> 4) * 4;
  const int l31 = lane & 31;
  bf16* hw = hbuf[wid];
  const int T = (E + 31) >> 5;
  const int NW = gridDim.x * 4;

  for (int t = blockIdx.x * 4 + wid; t < T; t += NW) {
    const int e0 = t * 32;
    int e = e0 + l31;
    bool val = e < E;
    int ec = val ? e : E - 1;
    int2 pr = sPair[ec];
    int idr = val ? pr.y : -1;
    int ids = pr.x;

    // ---- gather: afr = relu(u[recv] + v[send]) ----
    int rid[2], sid[2];
#pragma unroll
    for (int mi = 0; mi < 2; ++mi) {
      int row = mi * 16 + l15;
      int rv = __shfl(idr, row);
      rid[mi] = rv < 0 ? 0 : rv;
      sid[mi] = __shfl(ids, row);
    }
    bf16x8 afr[2][4];
#pragma unroll
    for (int mi = 0; mi < 2; ++mi) {
      const bf16* up = uv + (size_t)rid[mi] * 256;
      const bf16* vp = uv + (size_t)sid[mi] * 256 + 128;
#pragma unroll
      for (int kk = 0; kk < 4; ++kk) {
        bf16x8 u8 = *(const bf16x8*)(up + kk * 32 + ka);
        bf16x8 v8 = *(const bf16x8*)(vp + kk * 32 + ka);
        bf16x8 h;
#pragma unroll
        for (int x = 0; x < 8; ++x) {
          float s = (float)u8[x] + (float)v8[x];
          h[x] = (bf16)(s > 0.f ? s : 0.f);
        }
        afr[mi][kk] = h;
      }
    }

    // ---- layer 2: acc[2][8] = h1 @ W2 (M=32, N=128, K=128) ----
    f32x4 acc[2][8];
#pragma unroll
    for (int mi = 0; mi < 2; ++mi)
#pragma unroll
      for (int ni = 0; ni < 8; ++ni) acc[mi][ni] = (f32x4){0.f, 0.f, 0.f, 0.f};
    __builtin_amdgcn_s_setprio(1);
#pragma unroll
    for (int kk = 0; kk < 4; ++kk) {
      const int k0 = kk * 32 + ka;
      bf16x8 b[8];
#pragma unroll
      for (int ni = 0; ni < 8; ++ni) {
        int c = ni * 16 + l15;
        b[ni] = *(const bf16x8*)(wm2t + (size_t)c * 128 + k0);
      }
#pragma unroll
      for (int mi = 0; mi < 2; ++mi)
#pragma unroll
        for (int ni = 0; ni < 8; ++ni)
          acc[mi][ni] = __builtin_amdgcn_mfma_f32_16x16x32_bf16(afr[mi][kk], b[ni], acc[mi][ni], 0, 0, 0);
    }
    __builtin_amdgcn_s_setprio(0);

    // ---- layer2 epilogue + a3 loads via 16-row half-slice, one mi-half at a time ----
    bf16x8 a3[2][4];
#pragma unroll
    for (int mi = 0; mi < 2; ++mi) {
#pragma unroll
      for (int ni = 0; ni < 8; ++ni) {
        int c = ni * 16 + l15;
        float bias = mb2[c];
#pragma unroll
        for (int j = 0; j < 4; ++j) {
          int row = rj + j;
          float v = acc[mi][ni][j] + bias;
          v = v > 0.f ? v : 0.f;
          int byte = row * 256 + ((c * 2) ^ ((row & 7) << 4));
          *(bf16*)((char*)hw + byte) = (bf16)v;
        }
      }
      asm volatile("s_waitcnt lgkmcnt(0)" ::: "memory");
      __builtin_amdgcn_sched_barrier(0);
#pragma unroll
      for (int kk = 0; kk < 4; ++kk) {
        int k0 = kk * 32 + ka;
        int byte = l15 * 256 + ((k0 * 2) ^ ((l15 & 7) << 4));
        a3[mi][kk] = *(const bf16x8*)((const char*)hw + byte);
      }
      asm volatile("s_waitcnt lgkmcnt(0)" ::: "memory");
      __builtin_amdgcn_sched_barrier(0);
    }

    // ---- layer 3: acc3[2][8] = h2 @ W3 ----
    f32x4 acc3[2][8];
#pragma unroll
    for (int mi = 0; mi < 2; ++mi)
#pragma unroll
      for (int ni = 0; ni < 8; ++ni) acc3[mi][ni] = (f32x4){0.f, 0.f, 0.f, 0.f};
    __builtin_amdgcn_s_setprio(1);
#pragma unroll
    for (int kk = 0; kk < 4; ++kk) {
      const int k0 = kk * 32 + ka;
      bf16x8 b[8];
#pragma unroll
      for (int ni = 0; ni < 8; ++ni) {
        int c = ni * 16 + l15;
        b[ni] = *(const bf16x8*)(wm3t + (size_t)c * 128 + k0);
      }
#pragma unroll
      for (int mi = 0; mi < 2; ++mi)
#pragma unroll
        for (int ni = 0; ni < 8; ++ni)
          acc3[mi][ni] = __builtin_amdgcn_mfma_f32_16x16x32_bf16(a3[mi][kk], b[ni], acc3[mi][ni], 0, 0, 0);
    }
    __builtin_amdgcn_s_setprio(0);

    seg_reduce(acc3, idr, lane, l15, rj, inbox);
  }
}

// ---------------- node kernel v3: 64-row tiles, 256 thr, 16KB reused h-buffer ----------------
__global__ __launch_bounds__(256) void node_kernel(const float* __restrict__ nodes,
                                                   const float* __restrict__ inbox,
                                                   const bf16* __restrict__ wn1t,
                                                   const bf16* __restrict__ wn2t,
                                                   const bf16* __restrict__ wn3t,
                                                   const float* __restrict__ nb1,
                                                   const float* __restrict__ nb2,
                                                   const float* __restrict__ nb3,
                                                   float* __restrict__ out) {
  __shared__ bf16 h[64 * 128];  // 16KB, reused for h1 then h2
  const int tid = threadIdx.x;
  const int lane = tid & 63, wid = tid >> 6;
  const int wm = wid >> 1, wn = wid & 1;
  const int rBase = wm * 32, cBase = wn * 64;
  const int l15 = lane & 15, ka = (lane >> 4) * 8, rj = (lane >> 4) * 4;
  const int nBase = blockIdx.x * 64;

  f32x4 acc[2][4];
#pragma unroll
  for (int mi = 0; mi < 2; ++mi)
#pragma unroll
    for (int ni = 0; ni < 4; ++ni) acc[mi][ni] = (f32x4){0.f, 0.f, 0.f, 0.f};
#pragma unroll
  for (int kk = 0; kk < 8; ++kk) {
    const int k0 = kk * 32 + ka;
    bf16x8 a[2], b[4];
#pragma unroll
    for (int mi = 0; mi < 2; ++mi) {
      int n = nBase + rBase + mi * 16 + l15;
      if (n > N_NODES - 1) n = N_NODES - 1;
      const float* src = (kk < 4) ? (nodes + (size_t)n * FEAT + k0)
                                  : (inbox + (size_t)n * FEAT + (k0 - 128));
      a[mi] = cvt_f32x8_bf16(src);
    }
#pragma unroll
    for (int ni = 0; ni < 4; ++ni) {
      int c = cBase + ni * 16 + l15;
      b[ni] = *(const bf16x8*)(wn1t + (size_t)c * 256 + k0);
    }
#pragma unroll
    for (int mi = 0; mi < 2; ++mi)
#pragma unroll
      for (int ni = 0; ni < 4; ++ni)
        acc[mi][ni] = __builtin_amdgcn_mfma_f32_16x16x32_bf16(a[mi], b[ni], acc[mi][ni], 0, 0, 0);
  }
#pragma unroll
  for (int mi = 0; mi < 2; ++mi)
#pragma unroll
    for (int ni = 0; ni < 4; ++ni) {
      int c = cBase + ni * 16 + l15;
      float bias = nb1[c];
#pragma unroll
      for (int j = 0; j < 4; ++j) {
        int r = rBase + mi * 16 + rj + j;
        float v = acc[mi][ni][j] + bias;
        v = v > 0.f ? v : 0.f;
        int byte = r * 256 + ((c * 2) ^ ((r & 7) << 4));
        *(bf16*)((char*)h + byte) = (bf16)v;
      }
    }
  __syncthreads();

#pragma unroll
  for (int mi = 0; mi < 2; ++mi)
#pragma unroll
    for (int ni = 0; ni < 4; ++ni) acc[mi][ni] = (f32x4){0.f, 0.f, 0.f, 0.f};
#pragma unroll
  for (int kk = 0; kk < 4; ++kk) {
    const int k0 = kk * 32 + ka;
    bf16x8 a[2], b[4];
#pragma unroll
    for (int mi = 0; mi < 2; ++mi) {
      int r = rBase + mi * 16 + l15;
      int byte = r * 256 + ((k0 * 2) ^ ((r & 7) << 4));
      a[mi] = *(const bf16x8*)((const char*)h + byte);
    }
#pragma unroll
    for (int ni = 0; ni < 4; ++ni) {
      int c = cBase + ni * 16 + l15;
      b[ni] = *(const bf16x8*)(wn2t + (size_t)c * 128 + k0);
    }
#pragma unroll
    for (int mi = 0; mi < 2; ++mi)
#pragma unroll
      for (int ni = 0; ni < 4; ++ni)
        acc[mi][ni] = __builtin_amdgcn_mfma_f32_16x16x32_bf16(a[mi], b[ni], acc[mi][ni], 0, 0, 0);
  }
  __syncthreads();  // all h1 reads done before overwrite
#pragma unroll
  for (int mi = 0; mi < 2; ++mi)
#pragma unroll
    for (int ni = 0; ni < 4; ++ni) {
      int c = cBase + ni * 16 + l15;
      float bias = nb2[c];
#pragma unroll
      for (int j = 0; j < 4; ++j) {
        int r = rBase + mi * 16 + rj + j;
        float v = acc[mi][ni][j] + bias;
        v = v > 0.f ? v : 0.f;
        int byte = r * 256 + ((c * 2) ^ ((r & 7) << 4));
        *(bf16*)((char*)h + byte) = (bf16)v;
      }
    }
  __syncthreads();

#pragma unroll
  for (int mi = 0; mi < 2; ++mi)
#pragma unroll
    for (int ni = 0; ni < 4; ++ni) acc[mi][ni] = (f32x4){0.f, 0.f, 0.f, 0.f};
#pragma unroll
  for (int kk = 0; kk < 4; ++kk) {
    const int k0 = kk * 32 + ka;
    bf16x8 a[2], b[4];
#pragma unroll
    for (int mi = 0; mi < 2; ++mi) {
      int r = rBase + mi * 16 + l15;
      int byte = r * 256 + ((k0 * 2) ^ ((r & 7) << 4));
      a[mi] = *(const bf16x8*)((const char*)h + byte);
    }
#pragma unroll
    for (int ni = 0; ni < 4; ++ni) {
      int c = cBase + ni * 16 + l15;
      b[ni] = *(const bf16x8*)(wn3t + (size_t)c * 128 + k0);
    }
#pragma unroll
    for (int mi = 0; mi < 2; ++mi)
#pragma unroll
      for (int ni = 0; ni < 4; ++ni)
        acc[mi][ni] = __builtin_amdgcn_mfma_f32_16x16x32_bf16(a[mi], b[ni], acc[mi][ni], 0, 0, 0);
  }
#pragma unroll
  for (int mi = 0; mi < 2; ++mi)
#pragma unroll
    for (int ni = 0; ni < 4; ++ni) {
      int c = cBase + ni * 16 + l15;
      float bias = nb3[c];
#pragma unroll
      for (int j = 0; j < 4; ++j) {
        int r = rBase + mi * 16 + rj + j;
        int n = nBase + r;
        if (n < N_NODES)
          out[(size_t)n * FEAT + c] = nodes[(size_t)n * FEAT + c] + acc[mi][ni][j] + bias;
      }
    }
}

extern "C" void kernel_launch(void* const* d_in, const int* in_sizes, int n_in,
                              void* d_out, int out_size, void* d_ws, size_t ws_size,
                              hipStream_t stream) {
  const float* nodes = (const float*)d_in[0];
  const int* senders = (const int*)d_in[1];
  const int* receivers = (const int*)d_in[2];
  const float* mw1 = (const float*)d_in[3];
  const float* mb1 = (const float*)d_in[4];
  const float* mw2 = (const float*)d_in[5];
  const float* mb2 = (const float*)d_in[6];
  const float* mw3 = (const float*)d_in[7];
  const float* mb3 = (const float*)d_in[8];
  const float* nw1 = (const float*)d_in[9];
  const float* nb1 = (const float*)d_in[10];
  const float* nw2 = (const float*)d_in[11];
  const float* nb2 = (const float*)d_in[12];
  const float* nw3 = (const float*)d_in[13];
  const float* nb3 = (const float*)d_in[14];
  float* out = (float*)d_out;
  const int E = in_sizes[1];

  char* ws = (char*)d_ws;
  bf16* uv = (bf16*)ws;
  bf16* w = (bf16*)(ws + UV_BYTES);
  char* p = ws + UV_BYTES + W_BYTES;
  float* inbox = (float*)p; p += INBOX_BYTES;
  int* offs = (int*)p; p += ((size_t)(N_NODES + 1) * 4 + 255) & ~255ull;
  int* cnt = (int*)p;
  size_t cntPad = ((size_t)N_NODES * 4 + 255) & ~255ull;
  p += cntPad;
  int* cur = (int*)p;  p += ((size_t)N_NODES * 4 + 255) & ~255ull;
  int* bsum = (int*)p; p += 512;
  int2* sPair = (int2*)p; p += ((size_t)E * 8 + 255) & ~255ull;

  const int SC = (E + 511) / 512;
  const int IB = (N_NODES * 32 + 511) / 512;
  const int UVB = (N_NODES + 127) / 128;
  const int HB = (E + 255) / 256;

  hipMemsetAsync(cnt, 0, cntPad + (size_t)N_NODES * 4, stream);   // cnt + cur
  prep_hist_kernel<<<PREP_BLOCKS + HB, 256, 0, stream>>>(mw1, mw2, mw3, nw1, nw2, nw3, w,
                                                         receivers, cnt, E);
  scan1_kernel<<<NB_SCAN, 512, 0, stream>>>(cnt, offs, bsum);
  scan2_kernel<<<1, 128, 0, stream>>>(bsum);
  scatter_inbox_uv_kernel<<<SC + IB + UVB, 512, 0, stream>>>(
      senders, receivers, offs, bsum, cur, sPair, cnt, mb3, inbox,
      nodes, w + WUV_OFF, mb1, uv, E);
  edge_kernel<<<EDGE_BLOCKS, 256, 0, stream>>>(uv, sPair, w + WM2_OFF, w + WM3_OFF,
                                               mb2, inbox, E);
  node_kernel<<<(N_NODES + 63) / 64, 256, 0, stream>>>(nodes, inbox, w + WN1_OFF, w + WN2_OFF,
                                                       w + WN3_OFF, nb1, nb2, nb3, out);
}

// Round 18
// 405.054 us; speedup vs baseline: 1.4835x; 1.4835x over previous
//
#include <hip/hip_runtime.h>
#include <hip/hip_bf16.h>
#include <stdint.h>

typedef __bf16 bf16;
typedef bf16 bf16x8 __attribute__((ext_vector_type(8)));
typedef float f32x4 __attribute__((ext_vector_type(4)));

#define N_NODES 50000
#define FEAT 128
#define NB_SCAN ((N_NODES + 511) / 512)   // 98 (512-thread scan blocks)

static constexpr size_t UV_BYTES    = (size_t)N_NODES * 256 * 2;    // 25.6 MB bf16 uv
static constexpr size_t INBOX_BYTES = (size_t)N_NODES * FEAT * 4;   // 25.6 MB f32 inbox

#define WUV_OFF 0        // [256][128]  combined (mw1 top|bottom) transposed
#define WM2_OFF 32768    // [128][128]
#define WM3_OFF 49152    // [128][128]
#define WN1_OFF 65536    // [128][256]
#define WN2_OFF 98304    // [128][128]
#define WN3_OFF 114688   // [128][128]
#define W_TOTAL 131072
static constexpr size_t W_BYTES = (size_t)W_TOTAL * 2;
#define PREP_BLOCKS ((W_TOTAL + 255) / 256)   // 512

__device__ __forceinline__ bf16x8 cvt_f32x8_bf16(const float* __restrict__ p) {
  float4 f0 = *(const float4*)p;
  float4 f1 = *(const float4*)(p + 4);
  bf16x8 t;
  t[0] = (bf16)f0.x; t[1] = (bf16)f0.y; t[2] = (bf16)f0.z; t[3] = (bf16)f0.w;
  t[4] = (bf16)f1.x; t[5] = (bf16)f1.y; t[6] = (bf16)f1.z; t[7] = (bf16)f1.w;
  return t;
}

// bijective XCD-chunked swizzle (m204 form)
__device__ __forceinline__ int xcd_swizzle(int bid, int nwg) {
  int q = nwg >> 3, r = nwg & 7;
  int xcd = bid & 7, idx = bid >> 3;
  return (xcd < r ? xcd * (q + 1) : r * (q + 1) + (xcd - r) * q) + idx;
}

// ---------------- fused: prep weights (blocks [0,512)) + hist (rest) ----------------
__global__ void prep_hist_kernel(const float* __restrict__ mw1, const float* __restrict__ mw2,
                                 const float* __restrict__ mw3, const float* __restrict__ nw1,
                                 const float* __restrict__ nw2, const float* __restrict__ nw3,
                                 bf16* __restrict__ w,
                                 const int* __restrict__ receivers, int* __restrict__ cnt, int E) {
  const int b = blockIdx.x;
  if (b < PREP_BLOCKS) {
    int i = b * 256 + threadIdx.x;
    if (i >= W_TOTAL) return;
    float v;
    if (i < WM2_OFF) {
      int c = i >> 7, k = i & 127;
      v = (c < 128) ? mw1[k * 128 + c] : mw1[(128 + k) * 128 + (c - 128)];
    } else if (i < WM3_OFF) {
      int j = i - WM2_OFF; int c = j >> 7, k = j & 127;
      v = mw2[k * 128 + c];
    } else if (i < WN1_OFF) {
      int j = i - WM3_OFF; int c = j >> 7, k = j & 127;
      v = mw3[k * 128 + c];
    } else if (i < WN2_OFF) {
      int j = i - WN1_OFF; int c = j >> 8, k = j & 255;
      v = nw1[k * 128 + c];
    } else if (i < WN3_OFF) {
      int j = i - WN2_OFF; int c = j >> 7, k = j & 127;
      v = nw2[k * 128 + c];
    } else {
      int j = i - WN3_OFF; int c = j >> 7, k = j & 127;
      v = nw3[k * 128 + c];
    }
    w[i] = (bf16)v;
  } else {
    int i = (b - PREP_BLOCKS) * 256 + threadIdx.x;
    if (i < E) atomicAdd(&cnt[receivers[i]], 1);
  }
}

// ---------------- scan1: 512-thread blocks over 50k counts ----------------
__global__ __launch_bounds__(512) void scan1_kernel(const int* __restrict__ cnt,
                                                    int* __restrict__ offs,
                                                    int* __restrict__ bsum) {
  __shared__ int s[512];
  const int tid = threadIdx.x;
  const int g = blockIdx.x * 512 + tid;
  int x = (g < N_NODES) ? cnt[g] : 0;
  s[tid] = x;
  __syncthreads();
  for (int off = 1; off < 512; off <<= 1) {
    int v = (tid >= off) ? s[tid - off] : 0;
    __syncthreads();
    s[tid] += v;
    __syncthreads();
  }
  if (g < N_NODES) offs[g] = s[tid] - x;
  if (tid == 511) bsum[blockIdx.x] = s[tid];
}

__global__ void scan2_kernel(int* __restrict__ bsum) {  // 1 block x 128, NB_SCAN=98
  __shared__ int s[128];
  const int tid = threadIdx.x;
  int x = (tid < NB_SCAN) ? bsum[tid] : 0;
  s[tid] = x;
  __syncthreads();
  for (int off = 1; off < 128; off <<= 1) {
    int v = (tid >= off) ? s[tid - off] : 0;
    __syncthreads();
    s[tid] += v;
    __syncthreads();
  }
  if (tid < NB_SCAN) bsum[tid] = s[tid] - x;
}

// ---------------- mega dispatch: scatter_ids(int2) + inbox_init + uv_gemm ----------------
__global__ __launch_bounds__(512) void scatter_inbox_uv_kernel(
    const int* __restrict__ senders, const int* __restrict__ receivers,
    const int* __restrict__ offs, const int* __restrict__ bsum, int* __restrict__ cur,
    int2* __restrict__ sPair,
    const int* __restrict__ cnt, const float* __restrict__ mb3, float* __restrict__ inbox,
    const float* __restrict__ nodes, const bf16* __restrict__ wuvt,
    const float* __restrict__ mb1, bf16* __restrict__ uv, int E) {
  const int SC = (E + 511) >> 9;
  const int IB = (N_NODES * 32 + 511) >> 9;
  const int b = blockIdx.x;
  const int tid = threadIdx.x;

  if (b < SC) {
    int i = b * 512 + tid;
    if (i < E) {
      int r = receivers[i];
      int slot = offs[r] + bsum[r >> 9] + atomicAdd(&cur[r], 1);
      sPair[slot] = make_int2(senders[i], r);   // one 8B random write
    }
    return;
  }
  if (b < SC + IB) {
    int i = (b - SC) * 512 + tid;
    if (i >= N_NODES * 32) return;
    int n = i >> 5, q = i & 31;
    float c = (float)cnt[n];
    float4 bb = *(const float4*)(mb3 + q * 4);
    float4 o = {c * bb.x, c * bb.y, c * bb.z, c * bb.w};
    *(float4*)(inbox + (size_t)n * FEAT + q * 4) = o;
    return;
  }

  // ---- uv = nodes @ [W1a | W1b] (+b1 on u-half), bf16 out ----
  const int ub = b - SC - IB;
  const int lane = tid & 63, wid = tid >> 6;
  const int wm = wid >> 2, wn = wid & 3;
  const int rBase = ub * 128 + wm * 64;
  const int cBase = wn * 64;
  const int l15 = lane & 15, ka = (lane >> 4) * 8, rj = (lane >> 4) * 4;

  f32x4 acc[4][4];
#pragma unroll
  for (int mi = 0; mi < 4; ++mi)
#pragma unroll
    for (int ni = 0; ni < 4; ++ni) acc[mi][ni] = (f32x4){0.f, 0.f, 0.f, 0.f};

#pragma unroll
  for (int kk = 0; kk < 4; ++kk) {
    const int k0 = kk * 32 + ka;
    bf16x8 a[4], bb[4];
#pragma unroll
    for (int mi = 0; mi < 4; ++mi) {
      int r = rBase + mi * 16 + l15;
      if (r > N_NODES - 1) r = N_NODES - 1;
      a[mi] = cvt_f32x8_bf16(nodes + (size_t)r * FEAT + k0);
    }
#pragma unroll
    for (int ni = 0; ni < 4; ++ni) {
      int c = cBase + ni * 16 + l15;
      bb[ni] = *(const bf16x8*)(wuvt + (size_t)c * 128 + k0);
    }
#pragma unroll
    for (int mi = 0; mi < 4; ++mi)
#pragma unroll
      for (int ni = 0; ni < 4; ++ni)
        acc[mi][ni] = __builtin_amdgcn_mfma_f32_16x16x32_bf16(a[mi], bb[ni], acc[mi][ni], 0, 0, 0);
  }
#pragma unroll
  for (int mi = 0; mi < 4; ++mi)
#pragma unroll
    for (int ni = 0; ni < 4; ++ni) {
      int c = cBase + ni * 16 + l15;
      float bias = (c < FEAT) ? mb1[c] : 0.f;
#pragma unroll
      for (int j = 0; j < 4; ++j) {
        int r = rBase + mi * 16 + rj + j;
        if (r < N_NODES) uv[(size_t)r * 256 + c] = (bf16)(acc[mi][ni][j] + bias);
      }
    }
}

// ---- segmented reduce from accumulators: sorted ids -> ballot mask -> shfl combine ----
__device__ __forceinline__ void seg_reduce(const f32x4 (&acc3)[2][8], int idr,
                                           int lane, int l15, int rj,
                                           float* __restrict__ inbox) {
  int nxt = __shfl(idr, (lane & 31) + 1);
  bool bnd = ((lane & 31) == 31) || (idr != nxt);
  unsigned long long bm = __ballot(bnd);
  uint32_t mask = (uint32_t)(bm & 0xffffffffull);
  int lo = 0;
  while (mask) {
    int hi = __ffs(mask) - 1;   // inclusive boundary row
    mask &= mask - 1;
    int recv = __shfl(idr, hi);
    if (recv >= 0) {
      float s[8];
#pragma unroll
      for (int ni = 0; ni < 8; ++ni) {
        float x = 0.f;
#pragma unroll
        for (int mi = 0; mi < 2; ++mi)
#pragma unroll
          for (int j = 0; j < 4; ++j) {
            int row = mi * 16 + rj + j;
            x += (row >= lo && row <= hi) ? acc3[mi][ni][j] : 0.f;
          }
        x += __shfl_xor(x, 16);
        x += __shfl_xor(x, 32);
        s[ni] = x;
      }
      if (lane < 16) {
        float* dst = inbox + (size_t)recv * FEAT + l15;
#pragma unroll
        for (int ni = 0; ni < 8; ++ni) unsafeAtomicAdd(dst + ni * 16, s[ni]);
      }
    }
    lo = hi + 1;
  }
}

// ---------------- edge kernel v12: one-shot 32-edge tile per wave, int2 ids, XCD swizzle ----------------
__global__ __launch_bounds__(256, 3) void edge_kernel(const bf16* __restrict__ uv,
                                                      const int2* __restrict__ sPair,
                                                      const bf16* __restrict__ wm2t,
                                                      const bf16* __restrict__ wm3t,
                                                      const float* __restrict__ mb2,
                                                      float* __restrict__ inbox, int E) {
  __shared__ bf16 hbuf[4][16 * 128];  // 4KB per-wave half-tile transpose slice
  const int tid = threadIdx.x, lane = tid & 63, wid = tid >> 6;
  const int l15 = lane & 15, ka = (lane >> 4) * 8, rj = (lane >> 4) * 4;
  const int l31 = lane & 31;
  bf16* hw = hbuf[wid];

  const int swz = xcd_swizzle(blockIdx.x, gridDim.x);
  const int e0 = (swz * 4 + wid) * 32;
  if (e0 >= E) return;

  int e = e0 + l31;
  bool val = e < E;
  int ec = val ? e : E - 1;
  int2 pr = sPair[ec];
  int idr = val ? pr.y : -1;
  int ids = pr.x;

  // ---- gather: afr = relu(u[recv] + v[send]) ----
  int rid[2], sid[2];
#pragma unroll
  for (int mi = 0; mi < 2; ++mi) {
    int row = mi * 16 + l15;
    int rv = __shfl(idr, row);
    rid[mi] = rv < 0 ? 0 : rv;
    sid[mi] = __shfl(ids, row);
  }
  bf16x8 afr[2][4];
#pragma unroll
  for (int mi = 0; mi < 2; ++mi) {
    const bf16* up = uv + (size_t)rid[mi] * 256;
    const bf16* vp = uv + (size_t)sid[mi] * 256 + 128;
#pragma unroll
    for (int kk = 0; kk < 4; ++kk) {
      bf16x8 u8 = *(const bf16x8*)(up + kk * 32 + ka);
      bf16x8 v8 = *(const bf16x8*)(vp + kk * 32 + ka);
      bf16x8 h;
#pragma unroll
      for (int x = 0; x < 8; ++x) {
        float s = (float)u8[x] + (float)v8[x];
        h[x] = (bf16)(s > 0.f ? s : 0.f);
      }
      afr[mi][kk] = h;
    }
  }

  // ---- layer 2: acc[2][8] = h1 @ W2 (M=32, N=128, K=128) ----
  f32x4 acc[2][8];
#pragma unroll
  for (int mi = 0; mi < 2; ++mi)
#pragma unroll
    for (int ni = 0; ni < 8; ++ni) acc[mi][ni] = (f32x4){0.f, 0.f, 0.f, 0.f};
  __builtin_amdgcn_s_setprio(1);
#pragma unroll
  for (int kk = 0; kk < 4; ++kk) {
    const int k0 = kk * 32 + ka;
    bf16x8 b[8];
#pragma unroll
    for (int ni = 0; ni < 8; ++ni) {
      int c = ni * 16 + l15;
      b[ni] = *(const bf16x8*)(wm2t + (size_t)c * 128 + k0);
    }
#pragma unroll
    for (int mi = 0; mi < 2; ++mi)
#pragma unroll
      for (int ni = 0; ni < 8; ++ni)
        acc[mi][ni] = __builtin_amdgcn_mfma_f32_16x16x32_bf16(afr[mi][kk], b[ni], acc[mi][ni], 0, 0, 0);
  }
  __builtin_amdgcn_s_setprio(0);

  // ---- layer2 epilogue + a3 loads via 16-row half-slice, one mi-half at a time ----
  bf16x8 a3[2][4];
#pragma unroll
  for (int mi = 0; mi < 2; ++mi) {
#pragma unroll
    for (int ni = 0; ni < 8; ++ni) {
      int c = ni * 16 + l15;
      float bias = mb2[c];
#pragma unroll
      for (int j = 0; j < 4; ++j) {
        int row = rj + j;
        float v = acc[mi][ni][j] + bias;
        v = v > 0.f ? v : 0.f;
        int byte = row * 256 + ((c * 2) ^ ((row & 7) << 4));
        *(bf16*)((char*)hw + byte) = (bf16)v;
      }
    }
    asm volatile("s_waitcnt lgkmcnt(0)" ::: "memory");
    __builtin_amdgcn_sched_barrier(0);
#pragma unroll
    for (int kk = 0; kk < 4; ++kk) {
      int k0 = kk * 32 + ka;
      int byte = l15 * 256 + ((k0 * 2) ^ ((l15 & 7) << 4));
      a3[mi][kk] = *(const bf16x8*)((const char*)hw + byte);
    }
    asm volatile("s_waitcnt lgkmcnt(0)" ::: "memory");
    __builtin_amdgcn_sched_barrier(0);
  }

  // ---- layer 3: acc3[2][8] = h2 @ W3 ----
  f32x4 acc3[2][8];
#pragma unroll
  for (int mi = 0; mi < 2; ++mi)
#pragma unroll
    for (int ni = 0; ni < 8; ++ni) acc3[mi][ni] = (f32x4){0.f, 0.f, 0.f, 0.f};
  __builtin_amdgcn_s_setprio(1);
#pragma unroll
  for (int kk = 0; kk < 4; ++kk) {
    const int k0 = kk * 32 + ka;
    bf16x8 b[8];
#pragma unroll
    for (int ni = 0; ni < 8; ++ni) {
      int c = ni * 16 + l15;
      b[ni] = *(const bf16x8*)(wm3t + (size_t)c * 128 + k0);
    }
#pragma unroll
    for (int mi = 0; mi < 2; ++mi)
#pragma unroll
      for (int ni = 0; ni < 8; ++ni)
        acc3[mi][ni] = __builtin_amdgcn_mfma_f32_16x16x32_bf16(a3[mi][kk], b[ni], acc3[mi][ni], 0, 0, 0);
  }
  __builtin_amdgcn_s_setprio(0);

  seg_reduce(acc3, idr, lane, l15, rj, inbox);
}

// ---------------- node kernel v3: 64-row tiles, 256 thr, 16KB reused h-buffer ----------------
// 4 waves as 2(M)x2(N); wave = 32x64 quadrant; grid 782 blocks.
__global__ __launch_bounds__(256) void node_kernel(const float* __restrict__ nodes,
                                                   const float* __restrict__ inbox,
                                                   const bf16* __restrict__ wn1t,
                                                   const bf16* __restrict__ wn2t,
                                                   const bf16* __restrict__ wn3t,
                                                   const float* __restrict__ nb1,
                                                   const float* __restrict__ nb2,
                                                   const float* __restrict__ nb3,
                                                   float* __restrict__ out) {
  __shared__ bf16 h[64 * 128];  // 16KB, reused for h1 then h2
  const int tid = threadIdx.x;
  const int lane = tid & 63, wid = tid >> 6;
  const int wm = wid >> 1, wn = wid & 1;
  const int rBase = wm * 32, cBase = wn * 64;
  const int l15 = lane & 15, ka = (lane >> 4) * 8, rj = (lane >> 4) * 4;
  const int nBase = blockIdx.x * 64;

  f32x4 acc[2][4];
  // ---- layer 1: K=256 over [nodes | inbox] ----
#pragma unroll
  for (int mi = 0; mi < 2; ++mi)
#pragma unroll
    for (int ni = 0; ni < 4; ++ni) acc[mi][ni] = (f32x4){0.f, 0.f, 0.f, 0.f};
#pragma unroll
  for (int kk = 0; kk < 8; ++kk) {
    const int k0 = kk * 32 + ka;
    bf16x8 a[2], b[4];
#pragma unroll
    for (int mi = 0; mi < 2; ++mi) {
      int n = nBase + rBase + mi * 16 + l15;
      if (n > N_NODES - 1) n = N_NODES - 1;
      const float* src = (kk < 4) ? (nodes + (size_t)n * FEAT + k0)
                                  : (inbox + (size_t)n * FEAT + (k0 - 128));
      a[mi] = cvt_f32x8_bf16(src);
    }
#pragma unroll
    for (int ni = 0; ni < 4; ++ni) {
      int c = cBase + ni * 16 + l15;
      b[ni] = *(const bf16x8*)(wn1t + (size_t)c * 256 + k0);
    }
#pragma unroll
    for (int mi = 0; mi < 2; ++mi)
#pragma unroll
      for (int ni = 0; ni < 4; ++ni)
        acc[mi][ni] = __builtin_amdgcn_mfma_f32_16x16x32_bf16(a[mi], b[ni], acc[mi][ni], 0, 0, 0);
  }
#pragma unroll
  for (int mi = 0; mi < 2; ++mi)
#pragma unroll
    for (int ni = 0; ni < 4; ++ni) {
      int c = cBase + ni * 16 + l15;
      float bias = nb1[c];
#pragma unroll
      for (int j = 0; j < 4; ++j) {
        int r = rBase + mi * 16 + rj + j;
        float v = acc[mi][ni][j] + bias;
        v = v > 0.f ? v : 0.f;
        int byte = r * 256 + ((c * 2) ^ ((r & 7) << 4));
        *(bf16*)((char*)h + byte) = (bf16)v;
      }
    }
  __syncthreads();

  // ---- layer 2 ----
#pragma unroll
  for (int mi = 0; mi < 2; ++mi)
#pragma unroll
    for (int ni = 0; ni < 4; ++ni) acc[mi][ni] = (f32x4){0.f, 0.f, 0.f, 0.f};
#pragma unroll
  for (int kk = 0; kk < 4; ++kk) {
    const int k0 = kk * 32 + ka;
    bf16x8 a[2], b[4];
#pragma unroll
    for (int mi = 0; mi < 2; ++mi) {
      int r = rBase + mi * 16 + l15;
      int byte = r * 256 + ((k0 * 2) ^ ((r & 7) << 4));
      a[mi] = *(const bf16x8*)((const char*)h + byte);
    }
#pragma unroll
    for (int ni = 0; ni < 4; ++ni) {
      int c = cBase + ni * 16 + l15;
      b[ni] = *(const bf16x8*)(wn2t + (size_t)c * 128 + k0);
    }
#pragma unroll
    for (int mi = 0; mi < 2; ++mi)
#pragma unroll
      for (int ni = 0; ni < 4; ++ni)
        acc[mi][ni] = __builtin_amdgcn_mfma_f32_16x16x32_bf16(a[mi], b[ni], acc[mi][ni], 0, 0, 0);
  }
  __syncthreads();  // all h1 reads done before overwrite
#pragma unroll
  for (int mi = 0; mi < 2; ++mi)
#pragma unroll
    for (int ni = 0; ni < 4; ++ni) {
      int c = cBase + ni * 16 + l15;
      float bias = nb2[c];
#pragma unroll
      for (int j = 0; j < 4; ++j) {
        int r = rBase + mi * 16 + rj + j;
        float v = acc[mi][ni][j] + bias;
        v = v > 0.f ? v : 0.f;
        int byte = r * 256 + ((c * 2) ^ ((r & 7) << 4));
        *(bf16*)((char*)h + byte) = (bf16)v;
      }
    }
  __syncthreads();

  // ---- layer 3 + residual store ----
#pragma unroll
  for (int mi = 0; mi < 2; ++mi)
#pragma unroll
    for (int ni = 0; ni < 4; ++ni) acc[mi][ni] = (f32x4){0.f, 0.f, 0.f, 0.f};
#pragma unroll
  for (int kk = 0; kk < 4; ++kk) {
    const int k0 = kk * 32 + ka;
    bf16x8 a[2], b[4];
#pragma unroll
    for (int mi = 0; mi < 2; ++mi) {
      int r = rBase + mi * 16 + l15;
      int byte = r * 256 + ((k0 * 2) ^ ((r & 7) << 4));
      a[mi] = *(const bf16x8*)((const char*)h + byte);
    }
#pragma unroll
    for (int ni = 0; ni < 4; ++ni) {
      int c = cBase + ni * 16 + l15;
      b[ni] = *(const bf16x8*)(wn3t + (size_t)c * 128 + k0);
    }
#pragma unroll
    for (int mi = 0; mi < 2; ++mi)
#pragma unroll
      for (int ni = 0; ni < 4; ++ni)
        acc[mi][ni] = __builtin_amdgcn_mfma_f32_16x16x32_bf16(a[mi], b[ni], acc[mi][ni], 0, 0, 0);
  }
#pragma unroll
  for (int mi = 0; mi < 2; ++mi)
#pragma unroll
    for (int ni = 0; ni < 4; ++ni) {
      int c = cBase + ni * 16 + l15;
      float bias = nb3[c];
#pragma unroll
      for (int j = 0; j < 4; ++j) {
        int r = rBase + mi * 16 + rj + j;
        int n = nBase + r;
        if (n < N_NODES)
          out[(size_t)n * FEAT + c] = nodes[(size_t)n * FEAT + c] + acc[mi][ni][j] + bias;
      }
    }
}

extern "C" void kernel_launch(void* const* d_in, const int* in_sizes, int n_in,
                              void* d_out, int out_size, void* d_ws, size_t ws_size,
                              hipStream_t stream) {
  const float* nodes = (const float*)d_in[0];
  const int* senders = (const int*)d_in[1];
  const int* receivers = (const int*)d_in[2];
  const float* mw1 = (const float*)d_in[3];
  const float* mb1 = (const float*)d_in[4];
  const float* mw2 = (const float*)d_in[5];
  const float* mb2 = (const float*)d_in[6];
  const float* mw3 = (const float*)d_in[7];
  const float* mb3 = (const float*)d_in[8];
  const float* nw1 = (const float*)d_in[9];
  const float* nb1 = (const float*)d_in[10];
  const float* nw2 = (const float*)d_in[11];
  const float* nb2 = (const float*)d_in[12];
  const float* nw3 = (const float*)d_in[13];
  const float* nb3 = (const float*)d_in[14];
  float* out = (float*)d_out;
  const int E = in_sizes[1];

  char* ws = (char*)d_ws;
  bf16* uv = (bf16*)ws;
  bf16* w = (bf16*)(ws + UV_BYTES);
  char* p = ws + UV_BYTES + W_BYTES;
  float* inbox = (float*)p; p += INBOX_BYTES;
  int* offs = (int*)p; p += ((size_t)(N_NODES + 1) * 4 + 255) & ~255ull;
  int* cnt = (int*)p;
  size_t cntPad = ((size_t)N_NODES * 4 + 255) & ~255ull;
  p += cntPad;
  int* cur = (int*)p;  p += ((size_t)N_NODES * 4 + 255) & ~255ull;
  int* bsum = (int*)p; p += 512;
  int2* sPair = (int2*)p; p += ((size_t)E * 8 + 255) & ~255ull;

  const int SC = (E + 511) / 512;
  const int IB = (N_NODES * 32 + 511) / 512;
  const int UVB = (N_NODES + 127) / 128;
  const int HB = (E + 255) / 256;

  hipMemsetAsync(cnt, 0, cntPad + (size_t)N_NODES * 4, stream);   // cnt + cur
  prep_hist_kernel<<<PREP_BLOCKS + HB, 256, 0, stream>>>(mw1, mw2, mw3, nw1, nw2, nw3, w,
                                                         receivers, cnt, E);
  scan1_kernel<<<NB_SCAN, 512, 0, stream>>>(cnt, offs, bsum);
  scan2_kernel<<<1, 128, 0, stream>>>(bsum);
  scatter_inbox_uv_kernel<<<SC + IB + UVB, 512, 0, stream>>>(
      senders, receivers, offs, bsum, cur, sPair, cnt, mb3, inbox,
      nodes, w + WUV_OFF, mb1, uv, E);
  edge_kernel<<<(E + 127) / 128, 256, 0, stream>>>(uv, sPair, w + WM2_OFF, w + WM3_OFF,
                                                   mb2, inbox, E);
  node_kernel<<<(N_NODES + 63) / 64, 256, 0, stream>>>(nodes, inbox, w + WN1_OFF, w + WN2_OFF,
                                                       w + WN3_OFF, nb1, nb2, nb3, out);
}